// Round 4
// baseline (183.937 us; speedup 1.0000x reference)
//
#include <hip/hip_runtime.h>
#include <hip/hip_bf16.h>

#define B_DIM 4
#define C_DIM 192
#define T_SEQ 2048
#define H_DIM 2
#define K_DIM 96
#define BAND 256
#define IT 16            // q rows per attn block
#define NJT 34           // j-tiles of 16 in window (544 slots)
#define WSLOT 544        // padded window slots
#define WPD 556          // score row stride in dwords (16B aligned)
#define PRS (2*WPD)      // prob row stride in shorts (same buffer, bf16 overlay)
#define PMW 17           // packed-mask words per row
#define XSTR 200         // proj LDS row stride in shorts (400B: breaks 16-way conflict)
#define PDS 40           // pd row stride in shorts

typedef __attribute__((ext_vector_type(8))) short bf16x8;
typedef __attribute__((ext_vector_type(4))) short bf16x4;
typedef __attribute__((ext_vector_type(4))) float f32x4;
#define MFMA16 __builtin_amdgcn_mfma_f32_16x16x32_bf16

__device__ __forceinline__ short f2bf_bits(float f) {
    union { __hip_bfloat16 h; short s; } u; u.h = __float2bfloat16(f); return u.s;
}

// ---- workspace layout (bytes) ----
// WqT|WkT|WvT|WoT bf16 [192][192] (WqT prescaled); bqs fp32[192];
// relkbf bf16[16][96] (rows 9..15 zero); rvt bf16[96][32] (relv^T, cols 9..31 zero);
// qbf,kbf bf16 [bh][t][96]; vtb bf16 [bh][96][t]; obtc bf16 [b][t][192]
#define OFF_WT(m)  ((size_t)(m)*73728)
#define OFF_BQS    ((size_t)294912)
#define OFF_RELKBF ((size_t)295680)
#define OFF_RVT    ((size_t)298752)
#define OFF_QBF    ((size_t)304896)
#define OFF_KBF    (OFF_QBF + 3145728)
#define OFF_VTB    (OFF_KBF + 3145728)
#define OFF_OBTC   (OFF_VTB + 3145728)

// ---------------------------------------------------------------------------
// Prep: [0,144) LDS-tiled weight transpose (coalesced both sides);
// 144: scaled bias + rel-k + relv^T tables.
// ---------------------------------------------------------------------------
__global__ __launch_bounds__(256)
void prep_kernel(const float* __restrict__ Wq, const float* __restrict__ Wk,
                 const float* __restrict__ Wv, const float* __restrict__ Wo,
                 const float* __restrict__ bq, const float* __restrict__ relk,
                 const float* __restrict__ relv, char* __restrict__ ws)
{
    const float qscale = 0.10206207261596577f;   // 1/sqrt(96)
    const int bidx = blockIdx.x;
    const int tid  = threadIdx.x;

    if (bidx < 144) {                       // ---- 32x32 tile transpose via LDS
        __shared__ float tile[32][33];
        const int mi = bidx / 36, tl = bidx % 36;
        const int R0 = (tl / 6) * 32, C0 = (tl % 6) * 32;   // R0: c-rows, C0: d-cols
        const float* src = (mi == 0) ? Wq : (mi == 1) ? Wk : (mi == 2) ? Wv : Wo;
        const int r = tid >> 5, cc = tid & 31;
        #pragma unroll
        for (int i = 0; i < 4; ++i) {
            const int rr = r + 8*i;
            tile[rr][cc] = src[(R0 + rr)*C_DIM + C0 + cc];   // coalesced 128B
        }
        __syncthreads();
        short* dst = (short*)(ws + OFF_WT(mi));
        #pragma unroll
        for (int i = 0; i < 4; ++i) {
            const int rr = r + 8*i;                 // d-row within tile
            float v = tile[cc][rr];                 // bank-conflict-free (stride 33)
            if (mi == 0) v *= qscale;
            dst[(C0 + rr)*C_DIM + R0 + cc] = f2bf_bits(v);   // coalesced 64B
        }
        return;
    }
    if (tid < C_DIM)
        ((float*)(ws + OFF_BQS))[tid] = bq[tid]*qscale;
    short* rkb = (short*)(ws + OFF_RELKBF);
    for (int idx = tid; idx < 16*K_DIM; idx += 256) {
        const int row = idx / K_DIM;
        rkb[idx] = (row < 9) ? f2bf_bits(relk[idx]) : (short)0;
    }
    short* rvt = (short*)(ws + OFF_RVT);
    for (int idx = tid; idx < K_DIM*32; idx += 256) {
        const int col = idx >> 5, dd = idx & 31;
        rvt[idx] = (dd < 9) ? f2bf_bits(relv[dd*K_DIM + col]) : (short)0;
    }
}

// ---------------------------------------------------------------------------
// Kernel 1: q/k/v projection, one matrix per block (grid 1536 -> 6 blocks/CU,
// 24 waves/CU). Block = (b, 16 t, which in {q,k,v}), 4 waves x 3 d-tiles.
// XCD swizzle groups q/k/v of a tile + 64 neighbor tiles on one XCD.
// ---------------------------------------------------------------------------
__global__ __launch_bounds__(256, 6)
void proj_kernel(const float* __restrict__ x, const float* __restrict__ cin,
                 const float* __restrict__ bk, const float* __restrict__ bv,
                 char* __restrict__ ws)
{
    __shared__ short sb[IT*XSTR];   // [t][c] bf16, padded stride
    const int hw = blockIdx.x;
    const int L  = (hw & 7)*192 + (hw >> 3);   // 1536-block XCD-chunked swizzle
    const int which = L % 3;                   // 0=q, 1=k, 2=v
    const int rest  = L / 3;
    const int b  = rest >> 7;
    const int t0 = (rest & 127) * IT;
    const int tid = threadIdx.x;
    const int wave = tid >> 6, lane = tid & 63;
    const int q4 = lane >> 4, lr = lane & 15;

    const float* src = (which == 0) ? x : cin;
    for (int l = tid; l < 768; l += 256) {
        const int cr = l >> 2, u = l & 3;
        const float4 v4 = *reinterpret_cast<const float4*>(
            src + (size_t)(b*C_DIM + cr)*T_SEQ + t0 + 4*u);
        sb[(4*u+0)*XSTR + cr] = f2bf_bits(v4.x);
        sb[(4*u+1)*XSTR + cr] = f2bf_bits(v4.y);
        sb[(4*u+2)*XSTR + cr] = f2bf_bits(v4.z);
        sb[(4*u+3)*XSTR + cr] = f2bf_bits(v4.w);
    }
    __syncthreads();

    const short* WT = (const short*)(ws + OFF_WT(which));
    f32x4 a[3];
    #pragma unroll
    for (int j = 0; j < 3; ++j) a[j] = (f32x4){0.f,0.f,0.f,0.f};
    for (int kc = 0; kc < 6; ++kc) {
        const int ko = kc*32 + q4*8;
        const bf16x8 sf = *reinterpret_cast<const bf16x8*>(sb + lr*XSTR + ko);
        #pragma unroll
        for (int j = 0; j < 3; ++j) {
            const bf16x8 wf = *reinterpret_cast<const bf16x8*>(
                WT + ((3*wave + j)*16 + lr)*C_DIM + ko);
            a[j] = (which == 2) ? MFMA16(wf, sf, a[j], 0, 0, 0)    // v: m=d, n=t
                                : MFMA16(sf, wf, a[j], 0, 0, 0);   // q,k: m=t, n=d
        }
    }

    const float* bqs = (const float*)(ws + OFF_BQS);
    #pragma unroll
    for (int j = 0; j < 3; ++j) {
        const int dt = 3*wave + j;
        if (which <= 1) {    // q,k: col=d=dt*16+lr, row=t=q4*4+e
            const int d = dt*16 + lr, h = d/K_DIM, kk = d%K_DIM;
            const int bh = b*H_DIM + h;
            const float bias = (which == 0) ? bqs[d] : bk[d];
            short* dst = (short*)(ws + (which == 0 ? OFF_QBF : OFF_KBF));
            #pragma unroll
            for (int e = 0; e < 4; ++e) {
                const int t = t0 + q4*4 + e;
                dst[((size_t)bh*T_SEQ + t)*K_DIM + kk] = f2bf_bits(a[j][e] + bias);
            }
        } else {             // v: col=t=lr, row=d=dt*16+q4*4+e
            short* vtb = (short*)(ws + OFF_VTB);
            #pragma unroll
            for (int e = 0; e < 4; ++e) {
                const int d = dt*16 + q4*4 + e, h = d/K_DIM, kk = d%K_DIM;
                const int bh = b*H_DIM + h;
                vtb[((size_t)bh*K_DIM + kk)*T_SEQ + t0 + lr] = f2bf_bits(a[j][e] + bv[d]);
            }
        }
    }
}

// ---------------------------------------------------------------------------
// Kernel 2: banded attention, ONE head per block (grid 1024, 256 thr, 4 waves,
// 38 KB LDS -> 4 blocks/CU, 16 waves/CU, 4-wave barriers). Writes obtc slice.
// ---------------------------------------------------------------------------
__global__ __launch_bounds__(256, 4)
void attn_kernel(const int* __restrict__ mask, char* __restrict__ ws)
{
    __shared__ __align__(16) float ps[IT*WPD];  // 35.6 KB scores -> bf16 probs
    __shared__ float lt[257];                   // log1p table
    __shared__ __align__(16) char upool[1664];  // pm(1088)+rl(576) | pd(1280)
    unsigned* pm_s = (unsigned*)upool;          // [16][17]
    float*    rl   = (float*)(upool + 1088);    // [16][9]
    short*    pd_s = (short*)upool;             // [16][PDS]

    const short* qbf = (const short*)(ws + OFF_QBF);
    const short* kbf = (const short*)(ws + OFF_KBF);
    const short* vtb = (const short*)(ws + OFF_VTB);
    const short* rkb = (const short*)(ws + OFF_RELKBF);
    const short* rvt = (const short*)(ws + OFF_RVT);
    short* obtc = (short*)(ws + OFF_OBTC);

    const int L    = ((blockIdx.x & 7) << 7) + (blockIdx.x >> 3);  // XCD chunk
    const int b    = L >> 8;
    const int rem  = L & 255;
    const int i0   = (rem >> 1) * IT;
    const int head = rem & 1;                   // head pairs share an XCD (mask L2)
    const int tid = threadIdx.x;
    const int wave = tid >> 6, lane = tid & 63;
    const int q4 = lane >> 4, lr = lane & 15;

    const int jlo  = max(0, i0 - BAND);
    const int jhi  = min(T_SEQ - 1, i0 + IT - 1 + BAND);
    const int wlen = jhi - jlo + 1;
    const size_t qk_base = (size_t)(b*H_DIM + head) * T_SEQ * K_DIM;

    // ---- Q A-frags first (critical path of score phase)
    bf16x8 qa[3];
    {
        const short* qrow = qbf + qk_base + (size_t)(i0 + lr)*K_DIM + q4*8;
        #pragma unroll
        for (int kc = 0; kc < 3; ++kc)
            qa[kc] = *reinterpret_cast<const bf16x8*>(qrow + kc*32);
    }

    for (int idx = tid; idx < 257; idx += 256) lt[idx] = log1pf((float)idx);

    // ---- in-block mask bit-pack (272 words over 256 threads)
    for (int idx = tid; idx < IT*PMW; idx += 256) {
        const int r = idx / PMW, w = idx % PMW;
        const int* mrow = mask + ((size_t)b*T_SEQ + i0 + r)*T_SEQ;
        unsigned bits = 0;
        #pragma unroll
        for (int g4 = 0; g4 < 8; ++g4) {
            const int jg = jlo + 32*w + 4*g4;
            if (jg + 3 < T_SEQ) {
                const int4 mv = *reinterpret_cast<const int4*>(mrow + jg);
                bits |= (unsigned)(mv.x != 0) << (4*g4);
                bits |= (unsigned)(mv.y != 0) << (4*g4+1);
                bits |= (unsigned)(mv.z != 0) << (4*g4+2);
                bits |= (unsigned)(mv.w != 0) << (4*g4+3);
            } else {
                #pragma unroll
                for (int e = 0; e < 4; ++e)
                    if (jg + e < T_SEQ && mrow[jg+e] != 0) bits |= 1u << (4*g4+e);
            }
        }
        pm_s[idx] = bits;
    }

    // ---- scores (4 waves interleave j-tiles, 1-deep K prefetch)
    {
        int jt = wave;
        int jr = jlo + jt*16 + lr; if (jr > T_SEQ-1) jr = T_SEQ-1;
        const short* kr = kbf + qk_base + (size_t)jr*K_DIM + q4*8;
        bf16x8 kf0 = *reinterpret_cast<const bf16x8*>(kr);
        bf16x8 kf1 = *reinterpret_cast<const bf16x8*>(kr + 32);
        bf16x8 kf2 = *reinterpret_cast<const bf16x8*>(kr + 64);
        while (true) {
            const int jn = jt + 4;
            const bool more = (jn < NJT);
            bf16x8 nf0, nf1, nf2;
            if (more) {
                int jr2 = jlo + jn*16 + lr; if (jr2 > T_SEQ-1) jr2 = T_SEQ-1;
                const short* kr2 = kbf + qk_base + (size_t)jr2*K_DIM + q4*8;
                nf0 = *reinterpret_cast<const bf16x8*>(kr2);
                nf1 = *reinterpret_cast<const bf16x8*>(kr2 + 32);
                nf2 = *reinterpret_cast<const bf16x8*>(kr2 + 64);
            }
            f32x4 s = {0.f,0.f,0.f,0.f};
            s = MFMA16(qa[0], kf0, s, 0, 0, 0);
            s = MFMA16(qa[1], kf1, s, 0, 0, 0);
            s = MFMA16(qa[2], kf2, s, 0, 0, 0);
            float* pr = ps + (q4*4)*WPD + jt*16 + lr;
            pr[0*WPD] = s[0]; pr[1*WPD] = s[1]; pr[2*WPD] = s[2]; pr[3*WPD] = s[3];
            if (!more) break;
            kf0 = nf0; kf1 = nf1; kf2 = nf2;
            jt = jn;
        }
    }
    if (wave == 3) {                  // rl[r][dd] = q_r · relk_dd via MFMA
        const short* krow = rkb + lr*K_DIM + q4*8;
        f32x4 rs = {0.f,0.f,0.f,0.f};
        #pragma unroll
        for (int kc = 0; kc < 3; ++kc)
            rs = MFMA16(qa[kc], *reinterpret_cast<const bf16x8*>(krow + kc*32), rs, 0, 0, 0);
        if (lr < 9) {
            #pragma unroll
            for (int e = 0; e < 4; ++e)
                rl[(q4*4 + e)*9 + lr] = rs[e];
        }
    }
    __syncthreads();   // B1: scores, pm_s, lt, rl ready

    // ---- postprocess + softmax (row r by its 16 lanes)
    {
        const int r = tid >> 4, sj = tid & 15;
        const int i = i0 + r;
        float* prow = ps + r*WPD;
        float vals[36];
        float m = -INFINITY;
        #pragma unroll
        for (int mm = 0; mm < 9; ++mm) {
            const int j0 = 4*sj + 64*mm;
            float4 pv = make_float4(0.f,0.f,0.f,0.f);
            unsigned mb = 0;
            if (j0 < WSLOT) {
                pv = *reinterpret_cast<const float4*>(prow + j0);
                mb = pm_s[r*PMW + (j0 >> 5)] >> (j0 & 31);
            }
            const float pe[4] = {pv.x, pv.y, pv.z, pv.w};
            #pragma unroll
            for (int e = 0; e < 4; ++e) {
                const int j = j0 + e;
                float val = -INFINITY;
                if (j0 < WSLOT && j < wlen) {
                    const int jg = jlo + j, dd = jg - i;
                    const int ad = dd < 0 ? -dd : dd;
                    if (ad <= BAND && ((mb >> e) & 1)) {
                        val = pe[e] - lt[ad];
                        if ((unsigned)(dd + 4) <= 8u) val += rl[r*9 + dd + 4];
                    }
                }
                vals[mm*4 + e] = val;
                m = fmaxf(m, val);
            }
        }
        #pragma unroll
        for (int off = 8; off > 0; off >>= 1) m = fmaxf(m, __shfl_xor(m, off, 64));
        if (m == -INFINITY) m = 0.f;
        float ssum = 0.f;
        #pragma unroll
        for (int u = 0; u < 36; ++u) { vals[u] = __expf(vals[u] - m); ssum += vals[u]; }
        #pragma unroll
        for (int off = 8; off > 0; off >>= 1) ssum += __shfl_xor(ssum, off, 64);
        const float inv = ssum > 0.f ? 1.f/ssum : 0.f;
        short* pbrow = (short*)prow;
        #pragma unroll
        for (int mm = 0; mm < 9; ++mm) {
            const int j0 = 4*sj + 64*mm;
            if (j0 < WSLOT) {
                bf16x4 w;
                #pragma unroll
                for (int e = 0; e < 4; ++e) w[e] = f2bf_bits(vals[mm*4+e]*inv);
                *reinterpret_cast<bf16x4*>(pbrow + j0) = w;
            }
        }
    }
    __syncthreads();   // B2: bf16 probs ready; pm_s/rl dead -> pd pool reusable

    // ---- Pd fill (diagonal gather for rel_v MFMA); overlaps PV (both read probs)
    for (int idx = tid; idx < IT*PDS; idx += 256) {
        const int r = idx / PDS, kk = idx % PDS;
        short v = 0;
        if (kk < 9) {
            const int jg = i0 + r + kk - 4;
            if (jg >= 0 && jg < T_SEQ)
                v = ((const short*)ps)[r*PRS + (jg - jlo)];
        }
        pd_s[idx] = v;
    }

    // ---- PV (waves split 6 n-tiles 2/2/1/1, 1-deep V prefetch)
    const short* pbh = (const short*)ps;
    f32x4 o0 = {0.f,0.f,0.f,0.f}, o1 = {0.f,0.f,0.f,0.f};
    {
        const short* vbase0 = vtb + qk_base + (size_t)(wave*16 + lr)*T_SEQ;
        const short* vbase1 = vtb + qk_base + (size_t)((wave+4)*16 + lr)*T_SEQ;
        int tc = jlo + q4*8; if (tc > T_SEQ-8) tc = T_SEQ-8;
        bf16x8 vb0 = *reinterpret_cast<const bf16x8*>(vbase0 + tc);
        bf16x8 vb1 = {};
        if (wave < 2) vb1 = *reinterpret_cast<const bf16x8*>(vbase1 + tc);
        for (int kc = 0; kc < NJT/2; ++kc) {
            bf16x8 nv0, nv1;
            const bool more = (kc + 1 < NJT/2);
            if (more) {
                int tn = jlo + (kc+1)*32 + q4*8; if (tn > T_SEQ-8) tn = T_SEQ-8;
                nv0 = *reinterpret_cast<const bf16x8*>(vbase0 + tn);
                if (wave < 2) nv1 = *reinterpret_cast<const bf16x8*>(vbase1 + tn);
            }
            const bf16x8 pa = *reinterpret_cast<const bf16x8*>(pbh + lr*PRS + kc*32 + q4*8);
            o0 = MFMA16(pa, vb0, o0, 0, 0, 0);
            if (wave < 2) o1 = MFMA16(pa, vb1, o1, 0, 0, 0);
            if (more) { vb0 = nv0; if (wave < 2) vb1 = nv1; }
        }
    }
    __syncthreads();   // B3: pd ready

    // ---- rel_v contribution (one MFMA per n-tile) + store obtc slice
    {
        const bf16x8 pda = *reinterpret_cast<const bf16x8*>(pd_s + lr*PDS + q4*8);
        const bf16x8 rv0 = *reinterpret_cast<const bf16x8*>(rvt + (wave*16 + lr)*32 + q4*8);
        o0 = MFMA16(pda, rv0, o0, 0, 0, 0);
        if (wave < 2) {
            const bf16x8 rv1 = *reinterpret_cast<const bf16x8*>(rvt + ((wave+4)*16 + lr)*32 + q4*8);
            o1 = MFMA16(pda, rv1, o1, 0, 0, 0);
        }
    }
    #pragma unroll
    for (int u = 0; u < 2; ++u) {
        if (u == 1 && wave >= 2) break;
        const int nt = u ? wave + 4 : wave;
        const f32x4 oc = u ? o1 : o0;
        const int col = head*K_DIM + nt*16 + lr;
        #pragma unroll
        for (int e = 0; e < 4; ++e) {
            const int i = i0 + q4*4 + e;
            obtc[((size_t)b*T_SEQ + i)*C_DIM + col] = f2bf_bits(oc[e]);
        }
    }
}

// ---------------------------------------------------------------------------
// Kernel 3: output projection, bf16 MFMA, y^T form -> fp32 y[B,C,T].
// ---------------------------------------------------------------------------
__global__ __launch_bounds__(256)
void oproj_kernel(const float* __restrict__ bo, float* __restrict__ y,
                  const char* __restrict__ ws)
{
    const int bid = ((blockIdx.x & 7) << 6) + (blockIdx.x >> 3);   // XCD chunk
    const int b   = bid >> 7;
    const int t0  = (bid & 127) * 16;
    const int tid = threadIdx.x;
    const int wave = tid >> 6, lane = tid & 63;
    const int q4 = lane >> 4, lr = lane & 15;

    const short* WoT  = (const short*)(ws + OFF_WT(3));
    const short* obtc = (const short*)(ws + OFF_OBTC);

    f32x4 a[3];
    #pragma unroll
    for (int j = 0; j < 3; ++j) a[j] = (f32x4){0.f,0.f,0.f,0.f};
    for (int kc = 0; kc < 6; ++kc) {
        const int ko = kc*32 + q4*8;
        const bf16x8 bf = *reinterpret_cast<const bf16x8*>(
            obtc + ((size_t)b*T_SEQ + t0 + lr)*C_DIM + ko);
        #pragma unroll
        for (int j = 0; j < 3; ++j) {
            const bf16x8 af = *reinterpret_cast<const bf16x8*>(
                WoT + ((3*wave + j)*16 + lr)*C_DIM + ko);
            a[j] = MFMA16(af, bf, a[j], 0, 0, 0);
        }
    }
    #pragma unroll
    for (int j = 0; j < 3; ++j) {
        #pragma unroll
        for (int e = 0; e < 4; ++e) {
            const int d = (3*wave + j)*16 + q4*4 + e;
            y[((size_t)b*C_DIM + d)*T_SEQ + t0 + lr] = a[j][e] + bo[d];
        }
    }
}

// ---------------------------------------------------------------------------
extern "C" void kernel_launch(void* const* d_in, const int* in_sizes, int n_in,
                              void* d_out, int out_size, void* d_ws, size_t ws_size,
                              hipStream_t stream)
{
    const float* x    = (const float*)d_in[0];
    const float* c    = (const float*)d_in[1];
    const float* Wq   = (const float*)d_in[2];
    const float* bq   = (const float*)d_in[3];
    const float* Wk   = (const float*)d_in[4];
    const float* bk   = (const float*)d_in[5];
    const float* Wv   = (const float*)d_in[6];
    const float* bv   = (const float*)d_in[7];
    const float* Wo   = (const float*)d_in[8];
    const float* bo   = (const float*)d_in[9];
    const float* relk = (const float*)d_in[10];
    const float* relv = (const float*)d_in[11];
    const int*   mask = (const int*)d_in[12];
    float*       y    = (float*)d_out;
    char*        ws   = (char*)d_ws;

    hipLaunchKernelGGL(prep_kernel, dim3(145), dim3(256), 0, stream,
                       Wq, Wk, Wv, Wo, bq, relk, relv, ws);
    hipLaunchKernelGGL(proj_kernel, dim3(B_DIM*(T_SEQ/16)*3), dim3(256), 0, stream,
                       x, c, bk, bv, ws);
    hipLaunchKernelGGL(attn_kernel, dim3(B_DIM*H_DIM*(T_SEQ/IT)), dim3(256), 0, stream,
                       mask, ws);
    hipLaunchKernelGGL(oproj_kernel, dim3(B_DIM*(T_SEQ/16)), dim3(256), 0, stream,
                       bo, y, ws);
}

// Round 5
// 167.938 us; speedup vs baseline: 1.0953x; 1.0953x over previous
//
#include <hip/hip_runtime.h>
#include <hip/hip_bf16.h>

#define B_DIM 4
#define C_DIM 192
#define T_SEQ 2048
#define H_DIM 2
#define K_DIM 96
#define BAND 256
#define IT 32            // q rows per attn block (window still <= 544 slots)
#define NJT 34           // j-tiles of 16 in window
#define WSLOT 544        // padded window slots
#define WPD 556          // score row stride in dwords (16B aligned)
#define PRS (2*WPD)      // prob row stride in shorts (bf16 overlay of ps)
#define XSTR 200         // proj LDS row stride in shorts (breaks 16-way conflict)
#define PDS 40           // pd row stride in shorts

typedef __attribute__((ext_vector_type(8))) short bf16x8;
typedef __attribute__((ext_vector_type(4))) short bf16x4;
typedef __attribute__((ext_vector_type(4))) float f32x4;
#define MFMA16 __builtin_amdgcn_mfma_f32_16x16x32_bf16

__device__ __forceinline__ short f2bf_bits(float f) {
    union { __hip_bfloat16 h; short s; } u; u.h = __float2bfloat16(f); return u.s;
}

// ---- workspace layout (bytes) ----
// WqT|WkT|WvT|WoT bf16 [192][192] (WqT prescaled by qscale*log2e); bqs fp32[192];
// relkbf bf16[16][96] (rows 9..15 zero); rvt bf16[96][32] (relv^T, cols 9..31 zero);
// qbf,kbf bf16 [bh][t][96]; vtb bf16 [bh][96][t]; obtc bf16 [b][t][192]
#define OFF_WT(m)  ((size_t)(m)*73728)
#define OFF_BQS    ((size_t)294912)
#define OFF_RELKBF ((size_t)295680)
#define OFF_RVT    ((size_t)298752)
#define OFF_QBF    ((size_t)304896)
#define OFF_KBF    (OFF_QBF + 3145728)
#define OFF_VTB    (OFF_KBF + 3145728)
#define OFF_OBTC   (OFF_VTB + 3145728)

// ---------------------------------------------------------------------------
// Prep: [0,144) LDS-tiled weight transpose (coalesced both sides);
// 144: scaled bias + rel-k + relv^T tables.
// NOTE: qscale includes log2(e) -> scores come out in log2 domain, so the
// softmax uses exp2 (raw v_exp_f32) and a log2(1+d) proximal-bias table.
// ---------------------------------------------------------------------------
__global__ __launch_bounds__(256)
void prep_kernel(const float* __restrict__ Wq, const float* __restrict__ Wk,
                 const float* __restrict__ Wv, const float* __restrict__ Wo,
                 const float* __restrict__ bq, const float* __restrict__ relk,
                 const float* __restrict__ relv, char* __restrict__ ws)
{
    const float qscale = 0.14724445972f;   // (1/sqrt(96)) * log2(e)
    const int bidx = blockIdx.x;
    const int tid  = threadIdx.x;

    if (bidx < 144) {                       // ---- 32x32 tile transpose via LDS
        __shared__ float tile[32][33];
        const int mi = bidx / 36, tl = bidx % 36;
        const int R0 = (tl / 6) * 32, C0 = (tl % 6) * 32;   // R0: c-rows, C0: d-cols
        const float* src = (mi == 0) ? Wq : (mi == 1) ? Wk : (mi == 2) ? Wv : Wo;
        const int r = tid >> 5, cc = tid & 31;
        #pragma unroll
        for (int i = 0; i < 4; ++i) {
            const int rr = r + 8*i;
            tile[rr][cc] = src[(R0 + rr)*C_DIM + C0 + cc];   // coalesced 128B
        }
        __syncthreads();
        short* dst = (short*)(ws + OFF_WT(mi));
        #pragma unroll
        for (int i = 0; i < 4; ++i) {
            const int rr = r + 8*i;                 // d-row within tile
            float v = tile[cc][rr];                 // conflict-free (stride 33)
            if (mi == 0) v *= qscale;
            dst[(C0 + rr)*C_DIM + R0 + cc] = f2bf_bits(v);   // coalesced 64B
        }
        return;
    }
    if (tid < C_DIM)
        ((float*)(ws + OFF_BQS))[tid] = bq[tid]*qscale;
    short* rkb = (short*)(ws + OFF_RELKBF);
    for (int idx = tid; idx < 16*K_DIM; idx += 256) {
        const int row = idx / K_DIM;
        rkb[idx] = (row < 9) ? f2bf_bits(relk[idx]) : (short)0;
    }
    short* rvt = (short*)(ws + OFF_RVT);
    for (int idx = tid; idx < K_DIM*32; idx += 256) {
        const int col = idx >> 5, dd = idx & 31;
        rvt[idx] = (dd < 9) ? f2bf_bits(relv[dd*K_DIM + col]) : (short)0;
    }
}

// ---------------------------------------------------------------------------
// Kernel 1: q/k/v projection, one matrix per block, T=32 rows per block
// (weights amortized 2x vs T=16). Grid 768, 256 thr, 4 waves x 3 dt x 2 rt.
// ---------------------------------------------------------------------------
__global__ __launch_bounds__(256)
void proj_kernel(const float* __restrict__ x, const float* __restrict__ cin,
                 const float* __restrict__ bk, const float* __restrict__ bv,
                 char* __restrict__ ws)
{
    __shared__ short sb[2*IT*XSTR/2];   // [32 t][XSTR c] bf16 = 12.8 KB
    const int hw = blockIdx.x;
    const int L  = (hw & 7)*96 + (hw >> 3);    // 768-block XCD-chunked swizzle
    const int which = L % 3;                   // 0=q, 1=k, 2=v
    const int rest  = L / 3;                   // 0..255
    const int b  = rest >> 6;
    const int t0 = (rest & 63) * 32;
    const int tid = threadIdx.x;
    const int wave = tid >> 6, lane = tid & 63;
    const int q4 = lane >> 4, lr = lane & 15;

    const float* src = (which == 0) ? x : cin;
    for (int l = tid; l < 1536; l += 256) {    // 192 c-rows x 8 float4 chunks
        const int cr = l >> 3, u = l & 7;
        const float4 v4 = *reinterpret_cast<const float4*>(
            src + (size_t)(b*C_DIM + cr)*T_SEQ + t0 + 4*u);
        sb[(4*u+0)*XSTR + cr] = f2bf_bits(v4.x);
        sb[(4*u+1)*XSTR + cr] = f2bf_bits(v4.y);
        sb[(4*u+2)*XSTR + cr] = f2bf_bits(v4.z);
        sb[(4*u+3)*XSTR + cr] = f2bf_bits(v4.w);
    }
    __syncthreads();

    const short* WT = (const short*)(ws + OFF_WT(which));
    f32x4 a[3][2];
    #pragma unroll
    for (int j = 0; j < 3; ++j) {
        a[j][0] = (f32x4){0.f,0.f,0.f,0.f};
        a[j][1] = (f32x4){0.f,0.f,0.f,0.f};
    }
    for (int kc = 0; kc < 6; ++kc) {
        const int ko = kc*32 + q4*8;
        const bf16x8 sf0 = *reinterpret_cast<const bf16x8*>(sb + lr*XSTR + ko);
        const bf16x8 sf1 = *reinterpret_cast<const bf16x8*>(sb + (16 + lr)*XSTR + ko);
        #pragma unroll
        for (int j = 0; j < 3; ++j) {
            const bf16x8 wf = *reinterpret_cast<const bf16x8*>(
                WT + ((3*wave + j)*16 + lr)*C_DIM + ko);
            if (which == 2) {                      // v: m=d, n=t
                a[j][0] = MFMA16(wf, sf0, a[j][0], 0, 0, 0);
                a[j][1] = MFMA16(wf, sf1, a[j][1], 0, 0, 0);
            } else {                               // q,k: m=t, n=d
                a[j][0] = MFMA16(sf0, wf, a[j][0], 0, 0, 0);
                a[j][1] = MFMA16(sf1, wf, a[j][1], 0, 0, 0);
            }
        }
    }

    const float* bqs = (const float*)(ws + OFF_BQS);
    #pragma unroll
    for (int j = 0; j < 3; ++j) {
        const int dt = 3*wave + j;
        if (which <= 1) {    // q,k: col=d=dt*16+lr, row=t
            const int d = dt*16 + lr, h = d/K_DIM, kk = d%K_DIM;
            const int bh = b*H_DIM + h;
            const float bias = (which == 0) ? bqs[d] : bk[d];
            short* dst = (short*)(ws + (which == 0 ? OFF_QBF : OFF_KBF));
            #pragma unroll
            for (int rt = 0; rt < 2; ++rt)
                #pragma unroll
                for (int e = 0; e < 4; ++e) {
                    const int t = t0 + rt*16 + q4*4 + e;
                    dst[((size_t)bh*T_SEQ + t)*K_DIM + kk] = f2bf_bits(a[j][rt][e] + bias);
                }
        } else {             // v: col=t, row=d=dt*16+q4*4+e
            short* vtb = (short*)(ws + OFF_VTB);
            #pragma unroll
            for (int rt = 0; rt < 2; ++rt)
                #pragma unroll
                for (int e = 0; e < 4; ++e) {
                    const int d = dt*16 + q4*4 + e, h = d/K_DIM, kk = d%K_DIM;
                    const int bh = b*H_DIM + h;
                    vtb[((size_t)bh*K_DIM + kk)*T_SEQ + t0 + rt*16 + lr] =
                        f2bf_bits(a[j][rt][e] + bv[d]);
                }
        }
    }
}

// ---------------------------------------------------------------------------
// Kernel 2: banded attention, one head, IT=32 rows per block. 1024 threads
// (16 waves), 74.8 KB LDS -> 2 blocks/CU = 32 waves/CU (full TLP).
// Mask read directly as int4 in softmax (no pack phase). Base-2 softmax.
// ---------------------------------------------------------------------------
__global__ __launch_bounds__(1024, 8)
void attn_kernel(const int* __restrict__ mask, char* __restrict__ ws)
{
    __shared__ __align__(16) float ps[IT*WPD];  // 71168 B scores -> bf16 probs
    __shared__ float lt[257];                   // log2(1+d) table
    __shared__ __align__(16) char upool[2560];  // rl(1152) | pd(2560)
    float* rl   = (float*)upool;                // [32][9]
    short* pd_s = (short*)upool;                // [32][PDS] (after rl dead)

    const short* qbf = (const short*)(ws + OFF_QBF);
    const short* kbf = (const short*)(ws + OFF_KBF);
    const short* vtb = (const short*)(ws + OFF_VTB);
    const short* rkb = (const short*)(ws + OFF_RELKBF);
    const short* rvt = (const short*)(ws + OFF_RVT);
    short* obtc = (short*)(ws + OFF_OBTC);

    const int L    = ((blockIdx.x & 7) << 6) + (blockIdx.x >> 3);  // 512 blocks
    const int b    = L >> 7;
    const int rem  = L & 127;
    const int i0   = (rem >> 1) * IT;
    const int head = rem & 1;                   // head pairs share an XCD
    const int tid  = threadIdx.x;
    const int wave = tid >> 6, lane = tid & 63;
    const int q4 = lane >> 4, lr = lane & 15;
    const int ri = wave & 1, wg = wave >> 1;    // row-tile / job group

    const int jlo  = max(0, i0 - BAND);
    const int jhi  = min(T_SEQ - 1, i0 + IT - 1 + BAND);
    const int wlen = jhi - jlo + 1;             // <= 544
    const size_t qk_base = (size_t)(b*H_DIM + head) * T_SEQ * K_DIM;

    for (int idx = tid; idx < 257; idx += 1024) lt[idx] = log2f((float)(1 + idx));

    // ---- Q A-frags for this wave's row-tile
    bf16x8 qa[3];
    {
        const short* qrow = qbf + qk_base + (size_t)(i0 + ri*16 + lr)*K_DIM + q4*8;
        #pragma unroll
        for (int kc = 0; kc < 3; ++kc)
            qa[kc] = *reinterpret_cast<const bf16x8*>(qrow + kc*32);
    }

    // ---- scores: 68 (jt,ri) jobs over 16 waves; no reg prefetch (TLP hides)
    for (int jt = wg; jt < NJT; jt += 8) {
        int jr = jlo + jt*16 + lr;
        if (jr > T_SEQ-1) jr = T_SEQ-1;
        const short* krow = kbf + qk_base + (size_t)jr*K_DIM + q4*8;
        f32x4 s = {0.f,0.f,0.f,0.f};
        #pragma unroll
        for (int kc = 0; kc < 3; ++kc)
            s = MFMA16(qa[kc], *reinterpret_cast<const bf16x8*>(krow + kc*32), s, 0, 0, 0);
        float* pr = ps + (ri*16 + q4*4)*WPD + jt*16 + lr;
        pr[0*WPD] = s[0]; pr[1*WPD] = s[1]; pr[2*WPD] = s[2]; pr[3*WPD] = s[3];
    }
    if (wg == 7) {                    // rl[r][dd] = q_r . relk_dd (log2 domain)
        const short* krow = rkb + lr*K_DIM + q4*8;
        f32x4 rs = {0.f,0.f,0.f,0.f};
        #pragma unroll
        for (int kc = 0; kc < 3; ++kc)
            rs = MFMA16(qa[kc], *reinterpret_cast<const bf16x8*>(krow + kc*32), rs, 0, 0, 0);
        if (lr < 9) {
            #pragma unroll
            for (int e = 0; e < 4; ++e)
                rl[(ri*16 + q4*4 + e)*9 + lr] = rs[e];
        }
    }
    __syncthreads();   // B1: scores, lt, rl ready

    // ---- postprocess + softmax: row r by 32 lanes (tid>>5), base-2 domain
    {
        const int r = tid >> 5, sj = tid & 31;
        const int i = i0 + r;
        const int* mrow = mask + ((size_t)b*T_SEQ + i)*T_SEQ;
        float* prow = ps + r*WPD;
        float vals[20];
        float m = -INFINITY;
        #pragma unroll
        for (int mm = 0; mm < 5; ++mm) {
            const int j0 = 4*sj + 128*mm;
            float4 pv = make_float4(0.f,0.f,0.f,0.f);
            int4 mv = make_int4(0,0,0,0);
            if (j0 < wlen) {
                pv = *reinterpret_cast<const float4*>(prow + j0);
                mv = *reinterpret_cast<const int4*>(mrow + jlo + j0);  // jlo%4==0, j0%4==0 -> aligned, in-row
            }
            const float pe[4] = {pv.x, pv.y, pv.z, pv.w};
            const int me[4] = {mv.x, mv.y, mv.z, mv.w};
            #pragma unroll
            for (int e = 0; e < 4; ++e) {
                const int j = j0 + e;
                float val = -INFINITY;
                if (j0 < wlen && j < wlen) {
                    const int dd = jlo + j - i;
                    const int ad = dd < 0 ? -dd : dd;
                    if (ad <= BAND && me[e] != 0) {
                        val = pe[e] - lt[ad];
                        if ((unsigned)(dd + 4) <= 8u) val += rl[r*9 + dd + 4];
                    }
                }
                vals[mm*4 + e] = val;
                m = fmaxf(m, val);
            }
        }
        #pragma unroll
        for (int off = 16; off > 0; off >>= 1) m = fmaxf(m, __shfl_xor(m, off, 64));
        if (m == -INFINITY) m = 0.f;
        float ssum = 0.f;
        #pragma unroll
        for (int u = 0; u < 20; ++u) { vals[u] = exp2f(vals[u] - m); ssum += vals[u]; }
        #pragma unroll
        for (int off = 16; off > 0; off >>= 1) ssum += __shfl_xor(ssum, off, 64);
        const float inv = ssum > 0.f ? 1.f/ssum : 0.f;
        short* pbrow = (short*)prow;
        #pragma unroll
        for (int mm = 0; mm < 5; ++mm) {
            const int j0 = 4*sj + 128*mm;
            if (j0 < WSLOT) {
                bf16x4 w;
                #pragma unroll
                for (int e = 0; e < 4; ++e) w[e] = f2bf_bits(vals[mm*4+e]*inv);
                *reinterpret_cast<bf16x4*>(pbrow + j0) = w;
            }
        }
    }
    __syncthreads();   // B2: bf16 probs ready; rl dead -> pd pool reusable

    // ---- Pd fill (diagonal gather for rel_v MFMA)
    for (int idx = tid; idx < IT*PDS; idx += 1024) {
        const int r = idx / PDS, kk = idx % PDS;
        short v = 0;
        if (kk < 9) {
            const int jg = i0 + r + kk - 4;
            if (jg >= 0 && jg < T_SEQ)
                v = ((const short*)ps)[r*PRS + (jg - jlo)];
        }
        pd_s[idx] = v;
    }

    // ---- PV: 12 output tiles (2 row-tiles x 6 n-tiles) over waves 0..11
    f32x4 o = {0.f,0.f,0.f,0.f};
    const int pri = wave & 1, pnt = wave >> 1;
    if (wave < 12) {
        const short* pbh = (const short*)ps;
        const short* vbase = vtb + qk_base + (size_t)(pnt*16 + lr)*T_SEQ;
        for (int kc = 0; kc < NJT/2; ++kc) {
            const bf16x8 pa = *reinterpret_cast<const bf16x8*>(
                pbh + (pri*16 + lr)*PRS + kc*32 + q4*8);
            int tc = jlo + kc*32 + q4*8;
            if (tc > T_SEQ-8) tc = T_SEQ-8;
            const bf16x8 vb = *reinterpret_cast<const bf16x8*>(vbase + tc);
            o = MFMA16(pa, vb, o, 0, 0, 0);
        }
    }
    __syncthreads();   // B3: pd ready

    if (wave < 12) {
        // rel_v contribution: one MFMA
        const bf16x8 pda = *reinterpret_cast<const bf16x8*>(pd_s + (pri*16 + lr)*PDS + q4*8);
        const bf16x8 rv  = *reinterpret_cast<const bf16x8*>(rvt + (pnt*16 + lr)*32 + q4*8);
        o = MFMA16(pda, rv, o, 0, 0, 0);
        // store obtc slice
        const int col = head*K_DIM + pnt*16 + lr;
        #pragma unroll
        for (int e = 0; e < 4; ++e) {
            const int i = i0 + pri*16 + q4*4 + e;
            obtc[((size_t)b*T_SEQ + i)*C_DIM + col] = f2bf_bits(o[e]);
        }
    }
}

// ---------------------------------------------------------------------------
// Kernel 3: output projection, T=32 per block (weights amortized 2x).
// Grid 256, 256 thr, 4 waves x 3 dt x 2 rt. y^T store (m=d, n=t).
// ---------------------------------------------------------------------------
__global__ __launch_bounds__(256)
void oproj_kernel(const float* __restrict__ bo, float* __restrict__ y,
                  const char* __restrict__ ws)
{
    const int bid = ((blockIdx.x & 7) << 5) + (blockIdx.x >> 3);   // 256 blocks
    const int b   = bid >> 6;
    const int t0  = (bid & 63) * 32;
    const int tid = threadIdx.x;
    const int wave = tid >> 6, lane = tid & 63;
    const int q4 = lane >> 4, lr = lane & 15;

    const short* WoT  = (const short*)(ws + OFF_WT(3));
    const short* obtc = (const short*)(ws + OFF_OBTC);

    f32x4 a[3][2];
    #pragma unroll
    for (int j = 0; j < 3; ++j) {
        a[j][0] = (f32x4){0.f,0.f,0.f,0.f};
        a[j][1] = (f32x4){0.f,0.f,0.f,0.f};
    }
    for (int kc = 0; kc < 6; ++kc) {
        const int ko = kc*32 + q4*8;
        const bf16x8 bf0 = *reinterpret_cast<const bf16x8*>(
            obtc + ((size_t)b*T_SEQ + t0 + lr)*C_DIM + ko);
        const bf16x8 bf1 = *reinterpret_cast<const bf16x8*>(
            obtc + ((size_t)b*T_SEQ + t0 + 16 + lr)*C_DIM + ko);
        #pragma unroll
        for (int j = 0; j < 3; ++j) {
            const bf16x8 af = *reinterpret_cast<const bf16x8*>(
                WoT + ((3*wave + j)*16 + lr)*C_DIM + ko);
            a[j][0] = MFMA16(af, bf0, a[j][0], 0, 0, 0);
            a[j][1] = MFMA16(af, bf1, a[j][1], 0, 0, 0);
        }
    }
    #pragma unroll
    for (int j = 0; j < 3; ++j) {
        #pragma unroll
        for (int rt = 0; rt < 2; ++rt)
            #pragma unroll
            for (int e = 0; e < 4; ++e) {
                const int d = (3*wave + j)*16 + q4*4 + e;
                y[((size_t)b*C_DIM + d)*T_SEQ + t0 + rt*16 + lr] = a[j][rt][e] + bo[d];
            }
    }
}

// ---------------------------------------------------------------------------
extern "C" void kernel_launch(void* const* d_in, const int* in_sizes, int n_in,
                              void* d_out, int out_size, void* d_ws, size_t ws_size,
                              hipStream_t stream)
{
    const float* x    = (const float*)d_in[0];
    const float* c    = (const float*)d_in[1];
    const float* Wq   = (const float*)d_in[2];
    const float* bq   = (const float*)d_in[3];
    const float* Wk   = (const float*)d_in[4];
    const float* bk   = (const float*)d_in[5];
    const float* Wv   = (const float*)d_in[6];
    const float* bv   = (const float*)d_in[7];
    const float* Wo   = (const float*)d_in[8];
    const float* bo   = (const float*)d_in[9];
    const float* relk = (const float*)d_in[10];
    const float* relv = (const float*)d_in[11];
    const int*   mask = (const int*)d_in[12];
    float*       y    = (float*)d_out;
    char*        ws   = (char*)d_ws;

    hipLaunchKernelGGL(prep_kernel, dim3(145), dim3(256), 0, stream,
                       Wq, Wk, Wv, Wo, bq, relk, relv, ws);
    hipLaunchKernelGGL(proj_kernel, dim3(B_DIM*(T_SEQ/32)*3), dim3(256), 0, stream,
                       x, c, bk, bv, ws);
    hipLaunchKernelGGL(attn_kernel, dim3(B_DIM*H_DIM*(T_SEQ/IT)), dim3(1024), 0, stream,
                       mask, ws);
    hipLaunchKernelGGL(oproj_kernel, dim3(B_DIM*(T_SEQ/32)), dim3(256), 0, stream,
                       bo, y, ws);
}